// Round 1
// baseline (563.017 us; speedup 1.0000x reference)
//
#include <hip/hip_runtime.h>

typedef __attribute__((ext_vector_type(8))) short bf16x8;
typedef __attribute__((ext_vector_type(4))) float f32x4;

#define T_SEQ 2048

__device__ __forceinline__ unsigned short f2bf(float f) {
    unsigned int u = __builtin_bit_cast(unsigned int, f);
    u += 0x7fffu + ((u >> 16) & 1u);
    return (unsigned short)(u >> 16);
}

__device__ __forceinline__ void async16(void* lds, const void* g) {
    __builtin_amdgcn_global_load_lds(
        (__attribute__((address_space(1))) void*)g,
        (__attribute__((address_space(3))) void*)lds, 16, 0, 0);
}

// fp32 -> bf16 raw-bits conversion, 4 elems/thread
__global__ __launch_bounds__(256) void cvt_bf16(const float* __restrict__ src,
                                                unsigned short* __restrict__ dst, int n4) {
    int i = blockIdx.x * 256 + threadIdx.x;
    if (i < n4) {
        float4 v = ((const float4*)src)[i];
        ushort4 r;
        r.x = f2bf(v.x); r.y = f2bf(v.y); r.z = f2bf(v.z); r.w = f2bf(v.w);
        ((ushort4*)dst)[i] = r;
    }
}

// NT GEMM: out[m][n] = sum_k A[m][k]*B[n][k], M=8192, N=1024, K=1024.
// mode 0: bf16 out at [((b*16+h)*2048+t)*64+d]   (Q/K head-major)
// mode 1: bf16 out at [((b*16+h)*64+d)*2048+t]   (V transposed)
// mode 2: fp32 out at [m*1024+n]                 (final projection)
__global__ __launch_bounds__(256) void gemm_nt(const unsigned short* __restrict__ A,
                                               const unsigned short* __restrict__ B,
                                               void* __restrict__ out, int mode) {
    __shared__ unsigned short As[128 * 32];
    __shared__ unsigned short Bs[128 * 32];
    const int K = 1024;
    int m0 = blockIdx.y * 128, n0 = blockIdx.x * 128;
    int tid = threadIdx.x;
    int wave = tid >> 6, lane = tid & 63;
    int r = lane & 15, q = lane >> 4;
    int wr = wave >> 1, wc = wave & 1;

    f32x4 acc[4][4];
#pragma unroll
    for (int i = 0; i < 4; i++)
#pragma unroll
        for (int j = 0; j < 4; j++) acc[i][j] = (f32x4){0.f, 0.f, 0.f, 0.f};

    for (int k0 = 0; k0 < K; k0 += 32) {
#pragma unroll
        for (int i = 0; i < 2; i++) {
            int li = i * 256 + tid;
            int row = li >> 2, kk = (li & 3) << 3;
            // wave-uniform LDS base; HW scatters lane*16B
            async16(&As[i * 2048 + wave * 512], &A[(size_t)(m0 + row) * K + k0 + kk]);
            async16(&Bs[i * 2048 + wave * 512], &B[(size_t)(n0 + row) * K + k0 + kk]);
        }
        __syncthreads();
        bf16x8 af[4], bfr[4];
#pragma unroll
        for (int mi = 0; mi < 4; mi++)
            af[mi] = *(const bf16x8*)&As[(wr * 64 + mi * 16 + r) * 32 + q * 8];
#pragma unroll
        for (int ni = 0; ni < 4; ni++)
            bfr[ni] = *(const bf16x8*)&Bs[(wc * 64 + ni * 16 + r) * 32 + q * 8];
#pragma unroll
        for (int mi = 0; mi < 4; mi++)
#pragma unroll
            for (int ni = 0; ni < 4; ni++)
                acc[mi][ni] = __builtin_amdgcn_mfma_f32_16x16x32_bf16(
                    af[mi], bfr[ni], acc[mi][ni], 0, 0, 0);
        __syncthreads();
    }

    // C/D layout: col = lane&15, row = (lane>>4)*4 + reg  [m89-verified]
#pragma unroll
    for (int mi = 0; mi < 4; mi++) {
#pragma unroll
        for (int ni = 0; ni < 4; ni++) {
#pragma unroll
            for (int rr = 0; rr < 4; rr++) {
                int gm = m0 + wr * 64 + mi * 16 + q * 4 + rr;
                int gn = n0 + wc * 64 + ni * 16 + r;
                float v = acc[mi][ni][rr];
                if (mode == 0) {
                    int b = gm >> 11, t = gm & 2047;
                    int h = gn >> 6, d = gn & 63;
                    ((unsigned short*)out)[((size_t)(b * 16 + h) * 2048 + t) * 64 + d] = f2bf(v);
                } else if (mode == 1) {
                    int b = gm >> 11, t = gm & 2047;
                    int h = gn >> 6, d = gn & 63;
                    ((unsigned short*)out)[((size_t)(b * 16 + h) * 64 + d) * 2048 + t] = f2bf(v);
                } else {
                    ((float*)out)[(size_t)gm * 1024 + gn] = v;
                }
            }
        }
    }
}

// Flash-style attention with MASK_FILL=-10 semantics (masked keys DO contribute
// exp(-10-m)/Z weight, so we stream ALL T keys with explicit -10 fill).
// Block: 256 thr = 4 waves; wave w owns Q rows q0+w*16 .. +16. K-tile = 32 keys.
#define KS_STRIDE 72  // 64 d + pad, 144B = 16B-aligned rows
#define VS_STRIDE 40  // 32 k + pad, 80B  = 16B-aligned rows
__global__ __launch_bounds__(256) void attn(const unsigned short* __restrict__ Q,
                                            const unsigned short* __restrict__ Kg,
                                            const unsigned short* __restrict__ Vt,
                                            unsigned short* __restrict__ Y) {
    __shared__ unsigned short Ks[32 * KS_STRIDE];
    __shared__ unsigned short Vs[64 * VS_STRIDE];
    __shared__ unsigned short Ps[4][16 * VS_STRIDE];
    int bh = blockIdx.y;          // b*16+h
    int q0 = blockIdx.x * 64;
    int tid = threadIdx.x, wave = tid >> 6, lane = tid & 63;
    int r = lane & 15, qd = lane >> 4;

    // Q fragments held in registers for the whole block lifetime
    const unsigned short* qptr = Q + ((size_t)bh * T_SEQ + q0 + wave * 16 + r) * 64 + qd * 8;
    bf16x8 qf0 = *(const bf16x8*)qptr;        // d 0..31
    bf16x8 qf1 = *(const bf16x8*)(qptr + 32); // d 32..63

    float m_i[4], l_i[4];
    f32x4 o[4];
#pragma unroll
    for (int rr = 0; rr < 4; rr++) { m_i[rr] = -1e30f; l_i[rr] = 0.f; }
#pragma unroll
    for (int n = 0; n < 4; n++) o[n] = (f32x4){0.f, 0.f, 0.f, 0.f};
    int myrow[4];
#pragma unroll
    for (int rr = 0; rr < 4; rr++) myrow[rr] = q0 + wave * 16 + qd * 4 + rr;
    const float scale = 0.125f;

    int krow = tid >> 3, kds = (tid & 7) << 3;   // K tile: 32 rows x 64 d
    int vd = tid >> 2, vkk = (tid & 3) << 3;     // V tile: 64 d x 32 k
    const unsigned short* kgbase = Kg + ((size_t)bh * T_SEQ + krow) * 64 + kds;
    const unsigned short* vgbase = Vt + ((size_t)bh * 64 + vd) * T_SEQ + vkk;

    for (int k0 = 0; k0 < T_SEQ; k0 += 32) {
        __syncthreads();
        *(bf16x8*)&Ks[krow * KS_STRIDE + kds] = *(const bf16x8*)(kgbase + (size_t)k0 * 64);
        *(bf16x8*)&Vs[vd * VS_STRIDE + vkk] = *(const bf16x8*)(vgbase + k0);
        __syncthreads();

        // S = Q K^T : two 16x16 col tiles (keys k0..k0+15, k0+16..k0+31)
        f32x4 s0 = (f32x4){0.f, 0.f, 0.f, 0.f}, s1 = s0;
        {
            bf16x8 kf00 = *(const bf16x8*)&Ks[r * KS_STRIDE + qd * 8];
            bf16x8 kf01 = *(const bf16x8*)&Ks[r * KS_STRIDE + 32 + qd * 8];
            bf16x8 kf10 = *(const bf16x8*)&Ks[(16 + r) * KS_STRIDE + qd * 8];
            bf16x8 kf11 = *(const bf16x8*)&Ks[(16 + r) * KS_STRIDE + 32 + qd * 8];
            s0 = __builtin_amdgcn_mfma_f32_16x16x32_bf16(qf0, kf00, s0, 0, 0, 0);
            s0 = __builtin_amdgcn_mfma_f32_16x16x32_bf16(qf1, kf01, s0, 0, 0, 0);
            s1 = __builtin_amdgcn_mfma_f32_16x16x32_bf16(qf0, kf10, s1, 0, 0, 0);
            s1 = __builtin_amdgcn_mfma_f32_16x16x32_bf16(qf1, kf11, s1, 0, 0, 0);
        }
        // scale + causal fill (-10, exact reference semantics)
        int kg0 = k0 + r, kg1 = k0 + 16 + r;
#pragma unroll
        for (int rr = 0; rr < 4; rr++) {
            float v0 = (kg0 <= myrow[rr]) ? s0[rr] * scale : -10.0f;
            float v1 = (kg1 <= myrow[rr]) ? s1[rr] * scale : -10.0f;
            float mx = fmaxf(v0, v1);
#pragma unroll
            for (int off = 1; off < 16; off <<= 1) mx = fmaxf(mx, __shfl_xor(mx, off));
            float mn = fmaxf(m_i[rr], mx);
            float alpha = __expf(m_i[rr] - mn);
            m_i[rr] = mn;
            float p0 = __expf(v0 - mn);
            float p1 = __expf(v1 - mn);
            float sum = p0 + p1;
#pragma unroll
            for (int off = 1; off < 16; off <<= 1) sum += __shfl_xor(sum, off);
            l_i[rr] = l_i[rr] * alpha + sum;
#pragma unroll
            for (int n = 0; n < 4; n++) o[n][rr] *= alpha;
            // P in C-layout -> LDS row-major [qrow][key]
            Ps[wave][(qd * 4 + rr) * VS_STRIDE + r] = f2bf(p0);
            Ps[wave][(qd * 4 + rr) * VS_STRIDE + 16 + r] = f2bf(p1);
        }
        __syncthreads(); // order Ps cross-lane write->read (compiler fence)
        // P·V : P as A-operand, V as B-operand
        bf16x8 pf = *(const bf16x8*)&Ps[wave][r * VS_STRIDE + qd * 8];
#pragma unroll
        for (int n = 0; n < 4; n++) {
            bf16x8 vf = *(const bf16x8*)&Vs[(n * 16 + r) * VS_STRIDE + qd * 8];
            o[n] = __builtin_amdgcn_mfma_f32_16x16x32_bf16(pf, vf, o[n], 0, 0, 0);
        }
    }
    // epilogue: normalize, write Y as [B,T,H,D] bf16 (GEMM-ready [8192,1024])
    int b = bh >> 4, h = bh & 15;
#pragma unroll
    for (int n = 0; n < 4; n++) {
#pragma unroll
        for (int rr = 0; rr < 4; rr++) {
            float val = o[n][rr] / l_i[rr];
            Y[(((size_t)b * T_SEQ + myrow[rr]) * 16 + h) * 64 + n * 16 + r] = f2bf(val);
        }
    }
}

extern "C" void kernel_launch(void* const* d_in, const int* in_sizes, int n_in,
                              void* d_out, int out_size, void* d_ws, size_t ws_size,
                              hipStream_t stream) {
    const float* x  = (const float*)d_in[0];
    const float* wq = (const float*)d_in[1];
    const float* wk = (const float*)d_in[2];
    const float* wv = (const float*)d_in[3];
    const float* wo = (const float*)d_in[4];

    char* ws = (char*)d_ws;
    const size_t MB = 1u << 20;
    unsigned short* xb  = (unsigned short*)(ws);            // 16 MB (reused as Yb)
    unsigned short* Qb  = (unsigned short*)(ws + 16 * MB);  // 16 MB
    unsigned short* Kb  = (unsigned short*)(ws + 32 * MB);  // 16 MB
    unsigned short* Vtb = (unsigned short*)(ws + 48 * MB);  // 16 MB
    unsigned short* wqb = (unsigned short*)(ws + 64 * MB);  // 2 MB
    unsigned short* wkb = (unsigned short*)(ws + 66 * MB);
    unsigned short* wvb = (unsigned short*)(ws + 68 * MB);
    unsigned short* wob = (unsigned short*)(ws + 70 * MB);  // total 72 MB
    unsigned short* Yb  = xb;  // x dead after V projection

    cvt_bf16<<<8192, 256, 0, stream>>>(x, xb, 2097152);
    cvt_bf16<<<1024, 256, 0, stream>>>(wq, wqb, 262144);
    cvt_bf16<<<1024, 256, 0, stream>>>(wk, wkb, 262144);
    cvt_bf16<<<1024, 256, 0, stream>>>(wv, wvb, 262144);
    cvt_bf16<<<1024, 256, 0, stream>>>(wo, wob, 262144);

    dim3 ggrid(8, 64);
    gemm_nt<<<ggrid, 256, 0, stream>>>(xb, wqb, Qb, 0);
    gemm_nt<<<ggrid, 256, 0, stream>>>(xb, wkb, Kb, 0);
    gemm_nt<<<ggrid, 256, 0, stream>>>(xb, wvb, Vtb, 1);

    attn<<<dim3(32, 64), 256, 0, stream>>>(Qb, Kb, Vtb, Yb);

    gemm_nt<<<ggrid, 256, 0, stream>>>(Yb, wob, d_out, 2);
}

// Round 2
// 404.719 us; speedup vs baseline: 1.3911x; 1.3911x over previous
//
#include <hip/hip_runtime.h>

typedef __attribute__((ext_vector_type(8))) short bf16x8;
typedef __attribute__((ext_vector_type(4))) float f32x4;

#define T_SEQ 2048

__device__ __forceinline__ unsigned short f2bf(float f) {
    unsigned int u = __builtin_bit_cast(unsigned int, f);
    u += 0x7fffu + ((u >> 16) & 1u);
    return (unsigned short)(u >> 16);
}
__device__ __forceinline__ float bf2f(unsigned short u) {
    return __builtin_bit_cast(float, (unsigned int)u << 16);
}

__device__ __forceinline__ void async16(void* lds, const void* g) {
    __builtin_amdgcn_global_load_lds(
        (__attribute__((address_space(1))) void*)g,
        (__attribute__((address_space(3))) void*)lds, 16, 0, 0);
}

// fp32 -> bf16 raw-bits conversion, 4 elems/thread
__global__ __launch_bounds__(256) void cvt_bf16(const float* __restrict__ src,
                                                unsigned short* __restrict__ dst, int n4) {
    int i = blockIdx.x * 256 + threadIdx.x;
    if (i < n4) {
        float4 v = ((const float4*)src)[i];
        ushort4 r;
        r.x = f2bf(v.x); r.y = f2bf(v.y); r.z = f2bf(v.z); r.w = f2bf(v.w);
        ((ushort4*)dst)[i] = r;
    }
}

// NT GEMM: out[m][n] = sum_k A[m][k]*B[n][k], M=8192, N=1024, K=1024.
// mode 0: bf16 out at [((b*16+h)*2048+t)*64+d]   (Q/K head-major)
// mode 1: bf16 out at [((b*16+h)*64+d)*2048+t]   (V transposed)
// mode 2: fp32 out at [m*1024+n]                 (final projection)
__global__ __launch_bounds__(256) void gemm_nt(const unsigned short* __restrict__ A,
                                               const unsigned short* __restrict__ B,
                                               void* __restrict__ out, int mode) {
    __shared__ unsigned short As[128 * 32];
    __shared__ unsigned short Bs[128 * 32];
    const int K = 1024;
    int m0 = blockIdx.y * 128, n0 = blockIdx.x * 128;
    int tid = threadIdx.x;
    int wave = tid >> 6, lane = tid & 63;
    int r = lane & 15, q = lane >> 4;
    int wr = wave >> 1, wc = wave & 1;

    f32x4 acc[4][4];
#pragma unroll
    for (int i = 0; i < 4; i++)
#pragma unroll
        for (int j = 0; j < 4; j++) acc[i][j] = (f32x4){0.f, 0.f, 0.f, 0.f};

    for (int k0 = 0; k0 < K; k0 += 32) {
#pragma unroll
        for (int i = 0; i < 2; i++) {
            int li = i * 256 + tid;
            int row = li >> 2, kk = (li & 3) << 3;
            async16(&As[i * 2048 + wave * 512], &A[(size_t)(m0 + row) * K + k0 + kk]);
            async16(&Bs[i * 2048 + wave * 512], &B[(size_t)(n0 + row) * K + k0 + kk]);
        }
        __syncthreads();
        bf16x8 af[4], bfr[4];
#pragma unroll
        for (int mi = 0; mi < 4; mi++)
            af[mi] = *(const bf16x8*)&As[(wr * 64 + mi * 16 + r) * 32 + q * 8];
#pragma unroll
        for (int ni = 0; ni < 4; ni++)
            bfr[ni] = *(const bf16x8*)&Bs[(wc * 64 + ni * 16 + r) * 32 + q * 8];
#pragma unroll
        for (int mi = 0; mi < 4; mi++)
#pragma unroll
            for (int ni = 0; ni < 4; ni++)
                acc[mi][ni] = __builtin_amdgcn_mfma_f32_16x16x32_bf16(
                    af[mi], bfr[ni], acc[mi][ni], 0, 0, 0);
        __syncthreads();
    }

#pragma unroll
    for (int mi = 0; mi < 4; mi++) {
#pragma unroll
        for (int ni = 0; ni < 4; ni++) {
#pragma unroll
            for (int rr = 0; rr < 4; rr++) {
                int gm = m0 + wr * 64 + mi * 16 + q * 4 + rr;
                int gn = n0 + wc * 64 + ni * 16 + r;
                float v = acc[mi][ni][rr];
                if (mode == 0) {
                    int b = gm >> 11, t = gm & 2047;
                    int h = gn >> 6, d = gn & 63;
                    ((unsigned short*)out)[((size_t)(b * 16 + h) * 2048 + t) * 64 + d] = f2bf(v);
                } else if (mode == 1) {
                    int b = gm >> 11, t = gm & 2047;
                    int h = gn >> 6, d = gn & 63;
                    ((unsigned short*)out)[((size_t)(b * 16 + h) * 64 + d) * 2048 + t] = f2bf(v);
                } else {
                    ((float*)out)[(size_t)gm * 1024 + gn] = v;
                }
            }
        }
    }
}

// Suffix sums of V at 64-key granularity: SV[bh][j][d] = sum_{k >= 64j} V[bh][k][d]
// (fp32). One block per bh; reads Vt [bh][d][t].
__global__ __launch_bounds__(256) void suffix_sv(const unsigned short* __restrict__ Vt,
                                                 float* __restrict__ SV) {
    __shared__ float bsum[32][64];
    int bh = blockIdx.x;
    int d = threadIdx.x & 63, c = threadIdx.x >> 6;  // c: 8 j-blocks each
    const unsigned short* base = Vt + ((size_t)bh * 64 + d) * T_SEQ;
#pragma unroll
    for (int jj = 0; jj < 8; jj++) {
        int j = c * 8 + jj;
        float s = 0.f;
#pragma unroll
        for (int t8 = 0; t8 < 8; t8++) {
            bf16x8 v = *(const bf16x8*)(base + j * 64 + t8 * 8);
#pragma unroll
            for (int e = 0; e < 8; e++) s += bf2f((unsigned short)v[e]);
        }
        bsum[j][d] = s;
    }
    __syncthreads();
    if (threadIdx.x < 64) {
        float run = 0.f;
        for (int j = 31; j >= 0; j--) {
            run += bsum[j][d];
            SV[((size_t)bh * 32 + j) * 64 + d] = run;
        }
    }
}

// Flash attention, transposed-S scheme. MASK_FILL = -10 handled exactly:
// keys < q0+64 streamed with explicit -10 fill; keys >= q0+64 (all masked for
// this Q-tile) folded in analytically via SV suffix sums.
// Block: 256 thr = 4 waves; wave w owns queries q0+w*16..+15 (query = lane&15).
#define KST 72  // 64 + pad, 144B rows (16B aligned)
#define VST 72
#define PST 72
__global__ __launch_bounds__(256) void attn(const unsigned short* __restrict__ Q,
                                            const unsigned short* __restrict__ Kg,
                                            const unsigned short* __restrict__ Vt,
                                            const float* __restrict__ SV,
                                            unsigned short* __restrict__ Y) {
    __shared__ unsigned short Ks[64 * KST];   // [key][d]
    __shared__ unsigned short Vs[64 * VST];   // [d][key]
    __shared__ unsigned short Ps[4][16 * PST];// per wave: [query][key]
    int bh = blockIdx.y;
    int qi = 31 - blockIdx.x;  // heavy tiles dispatch first
    int q0 = qi * 64;
    int tid = threadIdx.x, wave = tid >> 6, lane = tid & 63;
    int r = lane & 15, qd = lane >> 4;
    int query = q0 + wave * 16 + r;

    const unsigned short* qptr = Q + ((size_t)bh * T_SEQ + query) * 64 + qd * 8;
    bf16x8 qf0 = *(const bf16x8*)qptr;         // d 0..31
    bf16x8 qf1 = *(const bf16x8*)(qptr + 32);  // d 32..63

    float m_i = -10.0f, l_i = 0.0f;            // floor m at -10 (tail logits)
    f32x4 o[4];                                // O^T: d = n*16+qd*4+reg, query = r
#pragma unroll
    for (int n = 0; n < 4; n++) o[n] = (f32x4){0.f, 0.f, 0.f, 0.f};

    int srow = tid >> 2, scol = (tid & 3) * 16;  // staging: 64 rows x 128B
    const unsigned short* kg = Kg + ((size_t)bh * T_SEQ + srow) * 64 + scol;
    const unsigned short* vg = Vt + ((size_t)bh * 64 + srow) * T_SEQ + scol;
    const float scale = 0.125f;

    int iters = qi + 1;
    for (int it = 0; it < iters; ++it) {
        int k0 = it * 64;
        __syncthreads();
        *(bf16x8*)&Ks[srow * KST + scol]     = *(const bf16x8*)(kg + (size_t)k0 * 64);
        *(bf16x8*)&Ks[srow * KST + scol + 8] = *(const bf16x8*)(kg + (size_t)k0 * 64 + 8);
        *(bf16x8*)&Vs[srow * VST + scol]     = *(const bf16x8*)(vg + k0);
        *(bf16x8*)&Vs[srow * VST + scol + 8] = *(const bf16x8*)(vg + k0 + 8);
        __syncthreads();

        // S^T tiles: row = key (qd*4+reg within 16-tile), col = query (r)
        f32x4 st[4];
#pragma unroll
        for (int t = 0; t < 4; t++) {
            bf16x8 kf0 = *(const bf16x8*)&Ks[(t * 16 + r) * KST + qd * 8];
            bf16x8 kf1 = *(const bf16x8*)&Ks[(t * 16 + r) * KST + 32 + qd * 8];
            st[t] = (f32x4){0.f, 0.f, 0.f, 0.f};
            st[t] = __builtin_amdgcn_mfma_f32_16x16x32_bf16(kf0, qf0, st[t], 0, 0, 0);
            st[t] = __builtin_amdgcn_mfma_f32_16x16x32_bf16(kf1, qf1, st[t], 0, 0, 0);
        }

        float v[4][4];
        bool anymask = (k0 + 63 > q0 + wave * 16);  // wave-uniform branch
        if (anymask) {
#pragma unroll
            for (int t = 0; t < 4; t++)
#pragma unroll
                for (int e = 0; e < 4; e++) {
                    int kgidx = k0 + t * 16 + qd * 4 + e;
                    v[t][e] = (kgidx <= query) ? st[t][e] * scale : -10.0f;
                }
        } else {
#pragma unroll
            for (int t = 0; t < 4; t++)
#pragma unroll
                for (int e = 0; e < 4; e++) v[t][e] = st[t][e] * scale;
        }

        float mx = -1e30f;
#pragma unroll
        for (int t = 0; t < 4; t++)
#pragma unroll
            for (int e = 0; e < 4; e++) mx = fmaxf(mx, v[t][e]);
        mx = fmaxf(mx, __shfl_xor(mx, 16));
        mx = fmaxf(mx, __shfl_xor(mx, 32));
        float mn = fmaxf(m_i, mx);
        float alpha = __expf(m_i - mn);
        m_i = mn;

        float p[4][4], sum = 0.f;
#pragma unroll
        for (int t = 0; t < 4; t++)
#pragma unroll
            for (int e = 0; e < 4; e++) { p[t][e] = __expf(v[t][e] - mn); sum += p[t][e]; }
        sum += __shfl_xor(sum, 16);
        sum += __shfl_xor(sum, 32);
        l_i = l_i * alpha + sum;
#pragma unroll
        for (int n = 0; n < 4; n++)
#pragma unroll
            for (int e = 0; e < 4; e++) o[n][e] *= alpha;

        // pack P -> LDS [query][key] (keys qd*4+e of tile t contiguous)
#pragma unroll
        for (int t = 0; t < 4; t++) {
            ushort4 pk;
            pk.x = f2bf(p[t][0]); pk.y = f2bf(p[t][1]);
            pk.z = f2bf(p[t][2]); pk.w = f2bf(p[t][3]);
            *(ushort4*)&Ps[wave][r * PST + t * 16 + qd * 4] = pk;
        }
        __syncthreads();

        // O^T += V * P^T : A = V-frag [d][key], B = P-frag [query][key]
        bf16x8 pf0 = *(const bf16x8*)&Ps[wave][r * PST + qd * 8];
        bf16x8 pf1 = *(const bf16x8*)&Ps[wave][r * PST + 32 + qd * 8];
#pragma unroll
        for (int n = 0; n < 4; n++) {
            bf16x8 vf0 = *(const bf16x8*)&Vs[(n * 16 + r) * VST + qd * 8];
            bf16x8 vf1 = *(const bf16x8*)&Vs[(n * 16 + r) * VST + 32 + qd * 8];
            o[n] = __builtin_amdgcn_mfma_f32_16x16x32_bf16(vf0, pf0, o[n], 0, 0, 0);
            o[n] = __builtin_amdgcn_mfma_f32_16x16x32_bf16(vf1, pf1, o[n], 0, 0, 0);
        }
    }

    // analytic tail: keys >= q0+64 all have logit -10 for every query in tile
    float pm = 0.f, tail_l = 0.f;
    float sv[4][4];
#pragma unroll
    for (int n = 0; n < 4; n++)
#pragma unroll
        for (int e = 0; e < 4; e++) sv[n][e] = 0.f;
    if (qi < 31) {
        pm = __expf(-10.0f - m_i);
        tail_l = (float)(T_SEQ - 64 * (qi + 1)) * pm;
        const float* svp = SV + ((size_t)bh * 32 + qi + 1) * 64;
#pragma unroll
        for (int n = 0; n < 4; n++) {
            float4 f = *(const float4*)(svp + n * 16 + qd * 4);
            sv[n][0] = f.x; sv[n][1] = f.y; sv[n][2] = f.z; sv[n][3] = f.w;
        }
    }
    float inv = 1.0f / (l_i + tail_l);
    int b = bh >> 4, h = bh & 15;
#pragma unroll
    for (int n = 0; n < 4; n++) {
        ushort4 yk;
        yk.x = f2bf((o[n][0] + pm * sv[n][0]) * inv);
        yk.y = f2bf((o[n][1] + pm * sv[n][1]) * inv);
        yk.z = f2bf((o[n][2] + pm * sv[n][2]) * inv);
        yk.w = f2bf((o[n][3] + pm * sv[n][3]) * inv);
        *(ushort4*)&Y[(((size_t)b * T_SEQ + query) * 16 + h) * 64 + n * 16 + qd * 4] = yk;
    }
}

extern "C" void kernel_launch(void* const* d_in, const int* in_sizes, int n_in,
                              void* d_out, int out_size, void* d_ws, size_t ws_size,
                              hipStream_t stream) {
    const float* x  = (const float*)d_in[0];
    const float* wq = (const float*)d_in[1];
    const float* wk = (const float*)d_in[2];
    const float* wv = (const float*)d_in[3];
    const float* wo = (const float*)d_in[4];

    char* ws = (char*)d_ws;
    const size_t MB = 1u << 20;
    unsigned short* xb  = (unsigned short*)(ws);            // 16 MB (reused as Yb)
    unsigned short* Qb  = (unsigned short*)(ws + 16 * MB);  // 16 MB
    unsigned short* Kb  = (unsigned short*)(ws + 32 * MB);  // 16 MB
    unsigned short* Vtb = (unsigned short*)(ws + 48 * MB);  // 16 MB
    unsigned short* wqb = (unsigned short*)(ws + 64 * MB);  // 2 MB
    unsigned short* wkb = (unsigned short*)(ws + 66 * MB);
    unsigned short* wvb = (unsigned short*)(ws + 68 * MB);
    unsigned short* wob = (unsigned short*)(ws + 70 * MB);  // total 72 MB
    unsigned short* Yb  = xb;                               // x dead after V proj
    float* SVf = (float*)d_out;  // 512 KB scratch; final gemm overwrites d_out after attn

    cvt_bf16<<<8192, 256, 0, stream>>>(x, xb, 2097152);
    cvt_bf16<<<1024, 256, 0, stream>>>(wq, wqb, 262144);
    cvt_bf16<<<1024, 256, 0, stream>>>(wk, wkb, 262144);
    cvt_bf16<<<1024, 256, 0, stream>>>(wv, wvb, 262144);
    cvt_bf16<<<1024, 256, 0, stream>>>(wo, wob, 262144);

    dim3 ggrid(8, 64);
    gemm_nt<<<ggrid, 256, 0, stream>>>(xb, wqb, Qb, 0);
    gemm_nt<<<ggrid, 256, 0, stream>>>(xb, wkb, Kb, 0);
    gemm_nt<<<ggrid, 256, 0, stream>>>(xb, wvb, Vtb, 1);

    suffix_sv<<<64, 256, 0, stream>>>(Vtb, SVf);

    attn<<<dim3(32, 64), 256, 0, stream>>>(Qb, Kb, Vtb, SVf, Yb);

    gemm_nt<<<ggrid, 256, 0, stream>>>(Yb, wob, d_out, 2);
}

// Round 3
// 349.586 us; speedup vs baseline: 1.6105x; 1.1577x over previous
//
#include <hip/hip_runtime.h>

typedef __attribute__((ext_vector_type(8))) short bf16x8;
typedef __attribute__((ext_vector_type(4))) float f32x4;

#define T_SEQ 2048
#define EXPM10 4.5399929762484854e-05f  // exp(-10)

__device__ __forceinline__ unsigned short f2bf(float f) {
    unsigned int u = __builtin_bit_cast(unsigned int, f);
    u += 0x7fffu + ((u >> 16) & 1u);
    return (unsigned short)(u >> 16);
}
__device__ __forceinline__ float bf2f(unsigned short u) {
    return __builtin_bit_cast(float, (unsigned int)u << 16);
}

__device__ __forceinline__ void async16(void* lds, const void* g) {
    __builtin_amdgcn_global_load_lds(
        (__attribute__((address_space(1))) void*)g,
        (__attribute__((address_space(3))) void*)lds, 16, 0, 0);
}

// fp32 -> bf16, 4 elems/thread (x activation)
__global__ __launch_bounds__(256) void cvt_bf16(const float* __restrict__ src,
                                                unsigned short* __restrict__ dst, int n4) {
    int i = blockIdx.x * 256 + threadIdx.x;
    if (i < n4) {
        float4 v = ((const float4*)src)[i];
        ushort4 r;
        r.x = f2bf(v.x); r.y = f2bf(v.y); r.z = f2bf(v.z); r.w = f2bf(v.w);
        ((ushort4*)dst)[i] = r;
    }
}

// all 4 weight matrices in one dispatch: wq/wk/wv -> contiguous wqkv, wo -> wob
__global__ __launch_bounds__(256) void cvt_w(const float* __restrict__ wq,
                                             const float* __restrict__ wk,
                                             const float* __restrict__ wv,
                                             const float* __restrict__ wo,
                                             unsigned short* __restrict__ wqkv,
                                             unsigned short* __restrict__ wob) {
    int which = blockIdx.x >> 10;  // 1024 blocks per matrix (262144 float4s)
    int i = (blockIdx.x & 1023) * 256 + threadIdx.x;
    const float* src = which == 0 ? wq : which == 1 ? wk : which == 2 ? wv : wo;
    unsigned short* dst = which < 3 ? wqkv + (size_t)which * 1048576 : wob;
    float4 v = ((const float4*)src)[i];
    ushort4 r;
    r.x = f2bf(v.x); r.y = f2bf(v.y); r.z = f2bf(v.z); r.w = f2bf(v.w);
    ((ushort4*)dst)[i] = r;
}

// Fused QKV projection: out[m][n] = sum_k x[m][k]*wqkv[n][k], M=8192, N=3072, K=1024.
// n<1024 -> Q head-major, n<2048 -> K head-major, else -> V transposed.
__global__ __launch_bounds__(256) void gemm_qkv(const unsigned short* __restrict__ A,
                                                const unsigned short* __restrict__ B,
                                                unsigned short* __restrict__ Qb,
                                                unsigned short* __restrict__ Kb,
                                                unsigned short* __restrict__ Vtb) {
    __shared__ unsigned short As[128 * 32];
    __shared__ unsigned short Bs[128 * 32];
    const int K = 1024;
    int m0 = blockIdx.y * 128, n0 = blockIdx.x * 128;
    int tid = threadIdx.x;
    int wave = tid >> 6, lane = tid & 63;
    int r = lane & 15, q = lane >> 4;
    int wr = wave >> 1, wc = wave & 1;

    f32x4 acc[4][4];
#pragma unroll
    for (int i = 0; i < 4; i++)
#pragma unroll
        for (int j = 0; j < 4; j++) acc[i][j] = (f32x4){0.f, 0.f, 0.f, 0.f};

    for (int k0 = 0; k0 < K; k0 += 32) {
#pragma unroll
        for (int i = 0; i < 2; i++) {
            int li = i * 256 + tid;
            int row = li >> 2, kk = (li & 3) << 3;
            async16(&As[i * 2048 + wave * 512], &A[(size_t)(m0 + row) * K + k0 + kk]);
            async16(&Bs[i * 2048 + wave * 512], &B[(size_t)(n0 + row) * K + k0 + kk]);
        }
        __syncthreads();
        bf16x8 af[4], bfr[4];
#pragma unroll
        for (int mi = 0; mi < 4; mi++)
            af[mi] = *(const bf16x8*)&As[(wr * 64 + mi * 16 + r) * 32 + q * 8];
#pragma unroll
        for (int ni = 0; ni < 4; ni++)
            bfr[ni] = *(const bf16x8*)&Bs[(wc * 64 + ni * 16 + r) * 32 + q * 8];
#pragma unroll
        for (int mi = 0; mi < 4; mi++)
#pragma unroll
            for (int ni = 0; ni < 4; ni++)
                acc[mi][ni] = __builtin_amdgcn_mfma_f32_16x16x32_bf16(
                    af[mi], bfr[ni], acc[mi][ni], 0, 0, 0);
        __syncthreads();
    }

#pragma unroll
    for (int mi = 0; mi < 4; mi++) {
#pragma unroll
        for (int ni = 0; ni < 4; ni++) {
#pragma unroll
            for (int rr = 0; rr < 4; rr++) {
                int gm = m0 + wr * 64 + mi * 16 + q * 4 + rr;
                int gn = n0 + wc * 64 + ni * 16 + r;
                float v = acc[mi][ni][rr];
                int b = gm >> 11, t = gm & 2047;
                int sel = gn >> 10, nn = gn & 1023;
                int h = nn >> 6, d = nn & 63;
                if (sel == 0)
                    Qb[((size_t)(b * 16 + h) * 2048 + t) * 64 + d] = f2bf(v);
                else if (sel == 1)
                    Kb[((size_t)(b * 16 + h) * 2048 + t) * 64 + d] = f2bf(v);
                else
                    Vtb[((size_t)(b * 16 + h) * 64 + d) * 2048 + t] = f2bf(v);
            }
        }
    }
}

// Final projection: out[m][n] = sum_k Y[m][k]*wo[n][k], fp32 out. M=8192,N=1024,K=1024.
__global__ __launch_bounds__(256) void gemm_out(const unsigned short* __restrict__ A,
                                                const unsigned short* __restrict__ B,
                                                float* __restrict__ out) {
    __shared__ unsigned short As[128 * 32];
    __shared__ unsigned short Bs[128 * 32];
    const int K = 1024;
    int m0 = blockIdx.y * 128, n0 = blockIdx.x * 128;
    int tid = threadIdx.x;
    int wave = tid >> 6, lane = tid & 63;
    int r = lane & 15, q = lane >> 4;
    int wr = wave >> 1, wc = wave & 1;

    f32x4 acc[4][4];
#pragma unroll
    for (int i = 0; i < 4; i++)
#pragma unroll
        for (int j = 0; j < 4; j++) acc[i][j] = (f32x4){0.f, 0.f, 0.f, 0.f};

    for (int k0 = 0; k0 < K; k0 += 32) {
#pragma unroll
        for (int i = 0; i < 2; i++) {
            int li = i * 256 + tid;
            int row = li >> 2, kk = (li & 3) << 3;
            async16(&As[i * 2048 + wave * 512], &A[(size_t)(m0 + row) * K + k0 + kk]);
            async16(&Bs[i * 2048 + wave * 512], &B[(size_t)(n0 + row) * K + k0 + kk]);
        }
        __syncthreads();
        bf16x8 af[4], bfr[4];
#pragma unroll
        for (int mi = 0; mi < 4; mi++)
            af[mi] = *(const bf16x8*)&As[(wr * 64 + mi * 16 + r) * 32 + q * 8];
#pragma unroll
        for (int ni = 0; ni < 4; ni++)
            bfr[ni] = *(const bf16x8*)&Bs[(wc * 64 + ni * 16 + r) * 32 + q * 8];
#pragma unroll
        for (int mi = 0; mi < 4; mi++)
#pragma unroll
            for (int ni = 0; ni < 4; ni++)
                acc[mi][ni] = __builtin_amdgcn_mfma_f32_16x16x32_bf16(
                    af[mi], bfr[ni], acc[mi][ni], 0, 0, 0);
        __syncthreads();
    }

#pragma unroll
    for (int mi = 0; mi < 4; mi++)
#pragma unroll
        for (int ni = 0; ni < 4; ni++)
#pragma unroll
            for (int rr = 0; rr < 4; rr++) {
                int gm = m0 + wr * 64 + mi * 16 + q * 4 + rr;
                int gn = n0 + wc * 64 + ni * 16 + r;
                out[(size_t)gm * 1024 + gn] = acc[mi][ni][rr];
            }
}

// Suffix sums of V at 64-key granularity: SV[bh][j][d] = sum_{k >= 64j} V[bh][k][d]
__global__ __launch_bounds__(256) void suffix_sv(const unsigned short* __restrict__ Vt,
                                                 float* __restrict__ SV) {
    __shared__ float bsum[32][64];
    int bh = blockIdx.x;
    int d = threadIdx.x & 63, c = threadIdx.x >> 6;
    const unsigned short* base = Vt + ((size_t)bh * 64 + d) * T_SEQ;
#pragma unroll
    for (int jj = 0; jj < 8; jj++) {
        int j = c * 8 + jj;
        float s = 0.f;
#pragma unroll
        for (int t8 = 0; t8 < 8; t8++) {
            bf16x8 v = *(const bf16x8*)(base + j * 64 + t8 * 8);
#pragma unroll
            for (int e = 0; e < 8; e++) s += bf2f((unsigned short)v[e]);
        }
        bsum[j][d] = s;
    }
    __syncthreads();
    if (threadIdx.x < 64) {
        float run = 0.f;
        for (int j = 31; j >= 0; j--) {
            run += bsum[j][d];
            SV[((size_t)bh * 32 + j) * 64 + d] = run;
        }
    }
}

// Flash attention, transposed-S, NO-MAX softmax (logits bounded << 88 so exp()
// never overflows; masked logit = -10 exactly -> p = exp(-10) const), analytic
// masked tail via SV suffix sums, register-prefetch pipelined K/V staging.
#define KST 72
#define VST 72
#define PST 72
__global__ __launch_bounds__(256) void attn(const unsigned short* __restrict__ Q,
                                            const unsigned short* __restrict__ Kg,
                                            const unsigned short* __restrict__ Vt,
                                            const float* __restrict__ SV,
                                            unsigned short* __restrict__ Y) {
    __shared__ unsigned short Ks[64 * KST];    // [key][d]
    __shared__ unsigned short Vs[64 * VST];    // [d][key]
    __shared__ unsigned short Ps[4][16 * PST]; // per wave: [query][key]
    int bh = blockIdx.y;
    int qi = 31 - blockIdx.x;  // heavy tiles first
    int q0 = qi * 64;
    int tid = threadIdx.x, wave = tid >> 6, lane = tid & 63;
    int r = lane & 15, qd = lane >> 4;
    int query = q0 + wave * 16 + r;

    const unsigned short* qptr = Q + ((size_t)bh * T_SEQ + query) * 64 + qd * 8;
    bf16x8 qf0 = *(const bf16x8*)qptr;
    bf16x8 qf1 = *(const bf16x8*)(qptr + 32);

    float l_lane = 0.0f;  // per-lane partial softmax denominator (reduced at end)
    f32x4 o[4];
#pragma unroll
    for (int n = 0; n < 4; n++) o[n] = (f32x4){0.f, 0.f, 0.f, 0.f};

    int srow = tid >> 2, scol = (tid & 3) * 16;  // staging: 64 rows x 128B
    const unsigned short* kg = Kg + ((size_t)bh * T_SEQ + srow) * 64 + scol;
    const unsigned short* vg = Vt + ((size_t)bh * 64 + srow) * T_SEQ + scol;
    const float scale = 0.125f;

    // prefetch tile 0 into registers
    bf16x8 pk0 = *(const bf16x8*)(kg);
    bf16x8 pk1 = *(const bf16x8*)(kg + 8);
    bf16x8 pv0 = *(const bf16x8*)(vg);
    bf16x8 pv1 = *(const bf16x8*)(vg + 8);

    int iters = qi + 1;
    for (int it = 0; it < iters; ++it) {
        __syncthreads();  // all waves done reading Ks/Vs of previous tile
        *(bf16x8*)&Ks[srow * KST + scol]     = pk0;
        *(bf16x8*)&Ks[srow * KST + scol + 8] = pk1;
        *(bf16x8*)&Vs[srow * VST + scol]     = pv0;
        *(bf16x8*)&Vs[srow * VST + scol + 8] = pv1;
        __syncthreads();
        // issue next tile's loads now; latency hidden behind this tile's compute
        if (it + 1 < iters) {
            size_t kn = (size_t)(it + 1) * 64;
            pk0 = *(const bf16x8*)(kg + kn * 64);
            pk1 = *(const bf16x8*)(kg + kn * 64 + 8);
            pv0 = *(const bf16x8*)(vg + kn);
            pv1 = *(const bf16x8*)(vg + kn + 8);
        }

        // S^T tiles: row = key, col = query(r)
        int k0 = it * 64;
        f32x4 st[4];
#pragma unroll
        for (int t = 0; t < 4; t++) {
            bf16x8 kf0 = *(const bf16x8*)&Ks[(t * 16 + r) * KST + qd * 8];
            bf16x8 kf1 = *(const bf16x8*)&Ks[(t * 16 + r) * KST + 32 + qd * 8];
            st[t] = (f32x4){0.f, 0.f, 0.f, 0.f};
            st[t] = __builtin_amdgcn_mfma_f32_16x16x32_bf16(kf0, qf0, st[t], 0, 0, 0);
            st[t] = __builtin_amdgcn_mfma_f32_16x16x32_bf16(kf1, qf1, st[t], 0, 0, 0);
        }

        // p = exp(logit); masked -> exp(-10) const. No max-tracking needed.
        float p[4][4], sum = 0.f;
        bool anymask = (k0 + 63 > q0 + wave * 16);  // wave-uniform
        if (anymask) {
#pragma unroll
            for (int t = 0; t < 4; t++)
#pragma unroll
                for (int e = 0; e < 4; e++) {
                    int kgidx = k0 + t * 16 + qd * 4 + e;
                    float pe = __expf(st[t][e] * scale);
                    p[t][e] = (kgidx <= query) ? pe : EXPM10;
                    sum += p[t][e];
                }
        } else {
#pragma unroll
            for (int t = 0; t < 4; t++)
#pragma unroll
                for (int e = 0; e < 4; e++) {
                    p[t][e] = __expf(st[t][e] * scale);
                    sum += p[t][e];
                }
        }
        l_lane += sum;

        // pack P -> per-wave LDS [query][key]
#pragma unroll
        for (int t = 0; t < 4; t++) {
            ushort4 pk;
            pk.x = f2bf(p[t][0]); pk.y = f2bf(p[t][1]);
            pk.z = f2bf(p[t][2]); pk.w = f2bf(p[t][3]);
            *(ushort4*)&Ps[wave][r * PST + t * 16 + qd * 4] = pk;
        }
        // Ps is wave-private; per-wave DS ops are in-order and may-alias keeps
        // compiler order. Pin schedule as insurance (no barrier needed).
        __builtin_amdgcn_sched_barrier(0);

        // O^T += V * P^T
        bf16x8 pf0 = *(const bf16x8*)&Ps[wave][r * PST + qd * 8];
        bf16x8 pf1 = *(const bf16x8*)&Ps[wave][r * PST + 32 + qd * 8];
#pragma unroll
        for (int n = 0; n < 4; n++) {
            bf16x8 vf0 = *(const bf16x8*)&Vs[(n * 16 + r) * VST + qd * 8];
            bf16x8 vf1 = *(const bf16x8*)&Vs[(n * 16 + r) * VST + 32 + qd * 8];
            o[n] = __builtin_amdgcn_mfma_f32_16x16x32_bf16(vf0, pf0, o[n], 0, 0, 0);
            o[n] = __builtin_amdgcn_mfma_f32_16x16x32_bf16(vf1, pf1, o[n], 0, 0, 0);
        }
    }

    // reduce l across the 4 qd-groups (disjoint key subsets per lane)
    float l_i = l_lane;
    l_i += __shfl_xor(l_i, 16);
    l_i += __shfl_xor(l_i, 32);

    // analytic tail: keys >= q0+64 all have logit exactly -10
    float pm = 0.f, tail_l = 0.f;
    float sv[4][4];
#pragma unroll
    for (int n = 0; n < 4; n++)
#pragma unroll
        for (int e = 0; e < 4; e++) sv[n][e] = 0.f;
    if (qi < 31) {
        pm = EXPM10;
        tail_l = (float)(T_SEQ - 64 * (qi + 1)) * pm;
        const float* svp = SV + ((size_t)bh * 32 + qi + 1) * 64;
#pragma unroll
        for (int n = 0; n < 4; n++) {
            float4 f = *(const float4*)(svp + n * 16 + qd * 4);
            sv[n][0] = f.x; sv[n][1] = f.y; sv[n][2] = f.z; sv[n][3] = f.w;
        }
    }
    float inv = 1.0f / (l_i + tail_l);
    int b = bh >> 4, h = bh & 15;
#pragma unroll
    for (int n = 0; n < 4; n++) {
        ushort4 yk;
        yk.x = f2bf((o[n][0] + pm * sv[n][0]) * inv);
        yk.y = f2bf((o[n][1] + pm * sv[n][1]) * inv);
        yk.z = f2bf((o[n][2] + pm * sv[n][2]) * inv);
        yk.w = f2bf((o[n][3] + pm * sv[n][3]) * inv);
        *(ushort4*)&Y[(((size_t)b * T_SEQ + query) * 16 + h) * 64 + n * 16 + qd * 4] = yk;
    }
}

extern "C" void kernel_launch(void* const* d_in, const int* in_sizes, int n_in,
                              void* d_out, int out_size, void* d_ws, size_t ws_size,
                              hipStream_t stream) {
    const float* x  = (const float*)d_in[0];
    const float* wq = (const float*)d_in[1];
    const float* wk = (const float*)d_in[2];
    const float* wv = (const float*)d_in[3];
    const float* wo = (const float*)d_in[4];

    char* ws = (char*)d_ws;
    const size_t MB = 1u << 20;
    unsigned short* xb   = (unsigned short*)(ws);            // 16 MB (reused as Yb)
    unsigned short* Qb   = (unsigned short*)(ws + 16 * MB);  // 16 MB
    unsigned short* Kb   = (unsigned short*)(ws + 32 * MB);  // 16 MB
    unsigned short* Vtb  = (unsigned short*)(ws + 48 * MB);  // 16 MB
    unsigned short* wqkv = (unsigned short*)(ws + 64 * MB);  // 6 MB (wq|wk|wv)
    unsigned short* wob  = (unsigned short*)(ws + 70 * MB);  // 2 MB -> total 72 MB
    unsigned short* Yb   = xb;                               // x dead after QKV proj
    float* SVf = (float*)d_out;  // scratch; final gemm overwrites d_out after attn

    cvt_bf16<<<8192, 256, 0, stream>>>(x, xb, 2097152);
    cvt_w<<<4096, 256, 0, stream>>>(wq, wk, wv, wo, wqkv, wob);

    gemm_qkv<<<dim3(24, 64), 256, 0, stream>>>(xb, wqkv, Qb, Kb, Vtb);

    suffix_sv<<<64, 256, 0, stream>>>(Vtb, SVf);

    attn<<<dim3(32, 64), 256, 0, stream>>>(Qb, Kb, Vtb, SVf, Yb);

    gemm_out<<<dim3(8, 64), 256, 0, stream>>>(Yb, wob, (float*)d_out);
}